// Round 13
// baseline (53.622 us; speedup 1.0000x reference)
//
#include <hip/hip_runtime.h>

// B=4, T=16, N=S=256, H=8, DK=DV=64, fp32 in/out.
// One block per (bt, h): 512 blocks x 512 threads (8 waves).
// Swapped QK^T (A=K, B=Q), no max-sub, scale*log2e folded into Q,
// permlane P exchange, V^T XOR bank-swizzle, plain coalesced stores.
// STREAMED K/V in four 64-row s-tiles, double-buffered LDS (36.9 KB).
// Round t: issue tile t+1 global loads -> regs; compute QKT+softmax+PV on
// tile t from LDS; write regs -> other LDS buffer; one barrier. Loads land
// under compute; barrier drain is trivial since the staged loads were
// already consumed by the LDS writes.

typedef short short8 __attribute__((ext_vector_type(8)));
typedef float floatx4 __attribute__((ext_vector_type(4)));

__device__ __forceinline__ unsigned cvt_pk(float lo, float hi) {
  unsigned r;
  asm("v_cvt_pk_bf16_f32 %0, %1, %2" : "=v"(r) : "v"(lo), "v"(hi));
  return r;
}

constexpr int KSTR  = 72;   // K tile row stride in shorts (144 B)
constexpr int VSTRW = 36;   // V^T tile row stride in u32 words (144 B)

__global__ __launch_bounds__(512, 4) void attn_kernel(
    const float* __restrict__ Q, const float* __restrict__ K,
    const float* __restrict__ V, float* __restrict__ O) {
  __shared__ __align__(16) short    Klds[2][64 * KSTR];   // 2 x 9216 B
  __shared__ __align__(16) unsigned Vt32[2][64 * VSTRW];  // 2 x 9216 B (36864 total)

  const int inst = blockIdx.x;
  const int h    = inst & 7;
  const int bt   = inst >> 3;
  const int base = bt * (256 * 512) + h * 64;
  const int tid  = threadIdx.x;

  const int wave = tid >> 6;
  const int lane = tid & 63;
  const int c    = lane & 15;
  const int g    = lane >> 4;
  const int c4   = tid & 15;
  const int sQ   = tid >> 4;       // 0..31

  const float* Kb = K + base;
  const float* Vb = V + base;

  // ---- Q fragments for BOTH passes, scaled by 0.125*log2(e) ----
  const float SCQ = 0.125f * 1.4426950408889634f;
  short8 qf[2][2];
  #pragma unroll
  for (int p = 0; p < 2; ++p) {
    #pragma unroll
    for (int ks2 = 0; ks2 < 2; ++ks2) {
      const float* qp =
          Q + base + (p * 128 + wave * 16 + c) * 512 + ks2 * 32 + g * 8;
      float4 a = *reinterpret_cast<const float4*>(qp);
      float4 b = *reinterpret_cast<const float4*>(qp + 4);
      union { unsigned u[4]; short8 s; } t;
      t.u[0] = cvt_pk(a.x * SCQ, a.y * SCQ);
      t.u[1] = cvt_pk(a.z * SCQ, a.w * SCQ);
      t.u[2] = cvt_pk(b.x * SCQ, b.y * SCQ);
      t.u[3] = cvt_pk(b.z * SCQ, b.w * SCQ);
      qf[p][ks2] = t.s;
    }
  }

  // ---- prologue: stage tile 0 directly into buffer 0 ----
  #pragma unroll
  for (int i = 0; i < 2; ++i) {
    int sr = i * 32 + sQ;          // 0..63
    float4 v = *reinterpret_cast<const float4*>(Kb + sr * 512 + c4 * 4);
    uint2 w;
    w.x = cvt_pk(v.x, v.y);
    w.y = cvt_pk(v.z, v.w);
    *reinterpret_cast<uint2*>(&Klds[0][sr * KSTR + c4 * 4]) = w;
  }
  {
    int spw = sQ ^ ((c4 & 7) << 2);
    float4 v0 = *reinterpret_cast<const float4*>(Vb + (2 * sQ) * 512 + c4 * 4);
    float4 v1 = *reinterpret_cast<const float4*>(Vb + (2 * sQ + 1) * 512 + c4 * 4);
    #pragma unroll
    for (int k = 0; k < 4; ++k)
      Vt32[0][(c4 * 4 + k) * VSTRW + spw] = cvt_pk((&v0.x)[k], (&v1.x)[k]);
  }
  __syncthreads();

#define KREAD(buf, ts, half)                                       \
  (*reinterpret_cast<const short8*>(                               \
      &Klds[buf][((ts) * 16 + c) * KSTR + (half) * 32 + g * 8]))
#define VREAD(buf, dt, ksc)                                        \
  (*reinterpret_cast<const short8*>(reinterpret_cast<const short*>(\
      &Vt32[buf][((dt) * 16 + c) * VSTRW +                         \
                 (((ksc) * 16 + 4 * g) ^ (16 * ((dt) & 1) + (c & 12)))])))

  floatx4 ao[2][4];
  #pragma unroll
  for (int p = 0; p < 2; ++p)
    #pragma unroll
    for (int dt = 0; dt < 4; ++dt) ao[p][dt] = floatx4{0.f, 0.f, 0.f, 0.f};
  float ps[2][4] = {{0.f, 0.f, 0.f, 0.f}, {0.f, 0.f, 0.f, 0.f}};

  #pragma unroll
  for (int t = 0; t < 4; ++t) {
    const int cur = t & 1, nxt = cur ^ 1;

    // -- issue tile t+1 global loads into registers (land under compute) --
    float4 kv0, kv1, vv0, vv1;
    if (t < 3) {
      kv0 = *reinterpret_cast<const float4*>(
          Kb + ((t + 1) * 64 + sQ) * 512 + c4 * 4);
      kv1 = *reinterpret_cast<const float4*>(
          Kb + ((t + 1) * 64 + 32 + sQ) * 512 + c4 * 4);
      vv0 = *reinterpret_cast<const float4*>(
          Vb + ((t + 1) * 64 + 2 * sQ) * 512 + c4 * 4);
      vv1 = *reinterpret_cast<const float4*>(
          Vb + ((t + 1) * 64 + 2 * sQ + 1) * 512 + c4 * 4);
    }

    // -- QK^T + exp2 + pack for the 4 16-row subtiles of this tile --
    unsigned pk[2][4][2];   // [pass][subtile][m]
    #pragma unroll
    for (int ts = 0; ts < 4; ++ts) {
      short8 kf0 = KREAD(cur, ts, 0);
      short8 kf1 = KREAD(cur, ts, 1);
      #pragma unroll
      for (int p = 0; p < 2; ++p) {
        floatx4 z = {0.f, 0.f, 0.f, 0.f};
        floatx4 a0 = __builtin_amdgcn_mfma_f32_16x16x32_bf16(kf0, qf[p][0], z, 0, 0, 0);
        floatx4 a1 = __builtin_amdgcn_mfma_f32_16x16x32_bf16(kf1, qf[p][1], z, 0, 0, 0);
        float e0 = exp2f(a0[0] + a1[0]);
        float e1 = exp2f(a0[1] + a1[1]);
        float e2 = exp2f(a0[2] + a1[2]);
        float e3 = exp2f(a0[3] + a1[3]);
        ps[p][0] += e0; ps[p][1] += e1; ps[p][2] += e2; ps[p][3] += e3;
        pk[p][ts][0] = cvt_pk(e0, e1);
        pk[p][ts][1] = cvt_pk(e2, e3);
      }
    }

    // -- PV: 2 s-chunks of 32 per tile --
    #pragma unroll
    for (int ksc = 0; ksc < 2; ++ksc) {
      union { unsigned u[4]; short8 s; } pa[2];
      #pragma unroll
      for (int p = 0; p < 2; ++p) {
        #pragma unroll
        for (int m = 0; m < 2; ++m) {
          unsigned x = pk[p][2 * ksc][m], y = pk[p][2 * ksc + 1][m];
          asm("v_permlane32_swap_b32 %0, %1" : "+v"(x), "+v"(y));
          asm("v_permlane16_swap_b32 %0, %1" : "+v"(x), "+v"(y));
          pa[p].u[m]     = x;
          pa[p].u[2 + m] = y;
        }
      }
      short8 vf0 = VREAD(cur, 0, ksc);
      short8 vf1 = VREAD(cur, 1, ksc);
      short8 vf2 = VREAD(cur, 2, ksc);
      short8 vf3 = VREAD(cur, 3, ksc);
      ao[0][0] = __builtin_amdgcn_mfma_f32_16x16x32_bf16(pa[0].s, vf0, ao[0][0], 0, 0, 0);
      ao[1][0] = __builtin_amdgcn_mfma_f32_16x16x32_bf16(pa[1].s, vf0, ao[1][0], 0, 0, 0);
      ao[0][1] = __builtin_amdgcn_mfma_f32_16x16x32_bf16(pa[0].s, vf1, ao[0][1], 0, 0, 0);
      ao[1][1] = __builtin_amdgcn_mfma_f32_16x16x32_bf16(pa[1].s, vf1, ao[1][1], 0, 0, 0);
      ao[0][2] = __builtin_amdgcn_mfma_f32_16x16x32_bf16(pa[0].s, vf2, ao[0][2], 0, 0, 0);
      ao[1][2] = __builtin_amdgcn_mfma_f32_16x16x32_bf16(pa[1].s, vf2, ao[1][2], 0, 0, 0);
      ao[0][3] = __builtin_amdgcn_mfma_f32_16x16x32_bf16(pa[0].s, vf3, ao[0][3], 0, 0, 0);
      ao[1][3] = __builtin_amdgcn_mfma_f32_16x16x32_bf16(pa[1].s, vf3, ao[1][3], 0, 0, 0);
    }

    // -- write tile t+1 into the other buffer (consumes in-flight loads;
    //    safe pre-barrier: no wave reads buf nxt during round t) --
    if (t < 3) {
      #pragma unroll
      for (int i = 0; i < 2; ++i) {
        float4 v = i ? kv1 : kv0;
        uint2 w;
        w.x = cvt_pk(v.x, v.y);
        w.y = cvt_pk(v.z, v.w);
        *reinterpret_cast<uint2*>(&Klds[nxt][(i * 32 + sQ) * KSTR + c4 * 4]) = w;
      }
      int spw = sQ ^ ((c4 & 7) << 2);
      #pragma unroll
      for (int k = 0; k < 4; ++k)
        Vt32[nxt][(c4 * 4 + k) * VSTRW + spw] = cvt_pk((&vv0.x)[k], (&vv1.x)[k]);
    }
    __syncthreads();
  }

  // ---- softmax denominators + epilogue (coalesced 64B row segments) ----
  #pragma unroll
  for (int p = 0; p < 2; ++p) {
    const int n0 = p * 128 + wave * 16;
    float s4 = (ps[p][0] + ps[p][1]) + (ps[p][2] + ps[p][3]);
    s4 += __shfl_xor(s4, 16);
    s4 += __shfl_xor(s4, 32);
    const float rcp = __builtin_amdgcn_rcpf(s4);
    float rcpv[4];
    #pragma unroll
    for (int r = 0; r < 4; ++r) rcpv[r] = __shfl(rcp, 4 * g + r);
    #pragma unroll
    for (int dt = 0; dt < 4; ++dt)
      #pragma unroll
      for (int r = 0; r < 4; ++r)
        O[base + (n0 + 4 * g + r) * 512 + dt * 16 + c] = ao[p][dt][r] * rcpv[r];
  }
#undef KREAD
#undef VREAD
}

extern "C" void kernel_launch(void* const* d_in, const int* in_sizes, int n_in,
                              void* d_out, int out_size, void* d_ws, size_t ws_size,
                              hipStream_t stream) {
  const float* Q = (const float*)d_in[0];
  const float* K = (const float*)d_in[1];
  const float* V = (const float*)d_in[2];
  float* O = (float*)d_out;
  attn_kernel<<<dim3(512), dim3(512), 0, stream>>>(Q, K, V, O);
}

// Round 17
// 53.230 us; speedup vs baseline: 1.0074x; 1.0074x over previous
//
#include <hip/hip_runtime.h>

// B=4, T=16, N=S=256, H=8, DK=DV=64, fp32 in/out.
// One block per (bt, h): 512 blocks x 512 threads (8 waves).
// Swapped QK^T (A=K, B=Q), no max-sub, scale*log2e folded into Q,
// permlane P exchange, V^T XOR bank-swizzle, plain coalesced stores.
// STREAMED K/V in four 64-row s-tiles, double-buffered LDS (36.9 KB).
// R13 spilled (compiler squeezed VGPR to 64 for 8 waves/SIMD). Fixes:
//   (1) amdgpu_waves_per_eu(4,4) pins the budget at 128 VGPR -> no spill;
//   (2) sched_barrier(0) after prefetch issue stops the scheduler from
//       sinking the tile t+1 loads below the compute phase.

typedef short short8 __attribute__((ext_vector_type(8)));
typedef float floatx4 __attribute__((ext_vector_type(4)));

__device__ __forceinline__ unsigned cvt_pk(float lo, float hi) {
  unsigned r;
  asm("v_cvt_pk_bf16_f32 %0, %1, %2" : "=v"(r) : "v"(lo), "v"(hi));
  return r;
}

constexpr int KSTR  = 72;   // K tile row stride in shorts (144 B)
constexpr int VSTRW = 36;   // V^T tile row stride in u32 words (144 B)

__global__ __launch_bounds__(512)
__attribute__((amdgpu_waves_per_eu(4, 4)))
void attn_kernel(
    const float* __restrict__ Q, const float* __restrict__ K,
    const float* __restrict__ V, float* __restrict__ O) {
  __shared__ __align__(16) short    Klds[2][64 * KSTR];   // 2 x 9216 B
  __shared__ __align__(16) unsigned Vt32[2][64 * VSTRW];  // 2 x 9216 B (36864 total)

  const int inst = blockIdx.x;
  const int h    = inst & 7;
  const int bt   = inst >> 3;
  const int base = bt * (256 * 512) + h * 64;
  const int tid  = threadIdx.x;

  const int wave = tid >> 6;
  const int lane = tid & 63;
  const int c    = lane & 15;
  const int g    = lane >> 4;
  const int c4   = tid & 15;
  const int sQ   = tid >> 4;       // 0..31

  const float* Kb = K + base;
  const float* Vb = V + base;

  // ---- Q fragments for BOTH passes, scaled by 0.125*log2(e) ----
  const float SCQ = 0.125f * 1.4426950408889634f;
  short8 qf[2][2];
  #pragma unroll
  for (int p = 0; p < 2; ++p) {
    #pragma unroll
    for (int ks2 = 0; ks2 < 2; ++ks2) {
      const float* qp =
          Q + base + (p * 128 + wave * 16 + c) * 512 + ks2 * 32 + g * 8;
      float4 a = *reinterpret_cast<const float4*>(qp);
      float4 b = *reinterpret_cast<const float4*>(qp + 4);
      union { unsigned u[4]; short8 s; } t;
      t.u[0] = cvt_pk(a.x * SCQ, a.y * SCQ);
      t.u[1] = cvt_pk(a.z * SCQ, a.w * SCQ);
      t.u[2] = cvt_pk(b.x * SCQ, b.y * SCQ);
      t.u[3] = cvt_pk(b.z * SCQ, b.w * SCQ);
      qf[p][ks2] = t.s;
    }
  }

  // ---- prologue: stage tile 0 directly into buffer 0 ----
  #pragma unroll
  for (int i = 0; i < 2; ++i) {
    int sr = i * 32 + sQ;          // 0..63
    float4 v = *reinterpret_cast<const float4*>(Kb + sr * 512 + c4 * 4);
    uint2 w;
    w.x = cvt_pk(v.x, v.y);
    w.y = cvt_pk(v.z, v.w);
    *reinterpret_cast<uint2*>(&Klds[0][sr * KSTR + c4 * 4]) = w;
  }
  {
    int spw = sQ ^ ((c4 & 7) << 2);
    float4 v0 = *reinterpret_cast<const float4*>(Vb + (2 * sQ) * 512 + c4 * 4);
    float4 v1 = *reinterpret_cast<const float4*>(Vb + (2 * sQ + 1) * 512 + c4 * 4);
    #pragma unroll
    for (int k = 0; k < 4; ++k)
      Vt32[0][(c4 * 4 + k) * VSTRW + spw] = cvt_pk((&v0.x)[k], (&v1.x)[k]);
  }
  __syncthreads();

#define KREAD(buf, ts, half)                                       \
  (*reinterpret_cast<const short8*>(                               \
      &Klds[buf][((ts) * 16 + c) * KSTR + (half) * 32 + g * 8]))
#define VREAD(buf, dt, ksc)                                        \
  (*reinterpret_cast<const short8*>(reinterpret_cast<const short*>(\
      &Vt32[buf][((dt) * 16 + c) * VSTRW +                         \
                 (((ksc) * 16 + 4 * g) ^ (16 * ((dt) & 1) + (c & 12)))])))

  floatx4 ao[2][4];
  #pragma unroll
  for (int p = 0; p < 2; ++p)
    #pragma unroll
    for (int dt = 0; dt < 4; ++dt) ao[p][dt] = floatx4{0.f, 0.f, 0.f, 0.f};
  float ps[2][4] = {{0.f, 0.f, 0.f, 0.f}, {0.f, 0.f, 0.f, 0.f}};

  #pragma unroll
  for (int t = 0; t < 4; ++t) {
    const int cur = t & 1, nxt = cur ^ 1;

    // -- issue tile t+1 global loads into registers (land under compute) --
    float4 kv0, kv1, vv0, vv1;
    if (t < 3) {
      kv0 = *reinterpret_cast<const float4*>(
          Kb + ((t + 1) * 64 + sQ) * 512 + c4 * 4);
      kv1 = *reinterpret_cast<const float4*>(
          Kb + ((t + 1) * 64 + 32 + sQ) * 512 + c4 * 4);
      vv0 = *reinterpret_cast<const float4*>(
          Vb + ((t + 1) * 64 + 2 * sQ) * 512 + c4 * 4);
      vv1 = *reinterpret_cast<const float4*>(
          Vb + ((t + 1) * 64 + 2 * sQ + 1) * 512 + c4 * 4);
    }
    // pin the prefetch above the compute phase (no sinking to use-site)
    __builtin_amdgcn_sched_barrier(0);

    // -- QK^T + exp2 + pack for the 4 16-row subtiles of this tile --
    unsigned pk[2][4][2];   // [pass][subtile][m]
    #pragma unroll
    for (int ts = 0; ts < 4; ++ts) {
      short8 kf0 = KREAD(cur, ts, 0);
      short8 kf1 = KREAD(cur, ts, 1);
      #pragma unroll
      for (int p = 0; p < 2; ++p) {
        floatx4 z = {0.f, 0.f, 0.f, 0.f};
        floatx4 a0 = __builtin_amdgcn_mfma_f32_16x16x32_bf16(kf0, qf[p][0], z, 0, 0, 0);
        floatx4 a1 = __builtin_amdgcn_mfma_f32_16x16x32_bf16(kf1, qf[p][1], z, 0, 0, 0);
        float e0 = exp2f(a0[0] + a1[0]);
        float e1 = exp2f(a0[1] + a1[1]);
        float e2 = exp2f(a0[2] + a1[2]);
        float e3 = exp2f(a0[3] + a1[3]);
        ps[p][0] += e0; ps[p][1] += e1; ps[p][2] += e2; ps[p][3] += e3;
        pk[p][ts][0] = cvt_pk(e0, e1);
        pk[p][ts][1] = cvt_pk(e2, e3);
      }
    }

    // -- PV: 2 s-chunks of 32 per tile --
    #pragma unroll
    for (int ksc = 0; ksc < 2; ++ksc) {
      union { unsigned u[4]; short8 s; } pa[2];
      #pragma unroll
      for (int p = 0; p < 2; ++p) {
        #pragma unroll
        for (int m = 0; m < 2; ++m) {
          unsigned x = pk[p][2 * ksc][m], y = pk[p][2 * ksc + 1][m];
          asm("v_permlane32_swap_b32 %0, %1" : "+v"(x), "+v"(y));
          asm("v_permlane16_swap_b32 %0, %1" : "+v"(x), "+v"(y));
          pa[p].u[m]     = x;
          pa[p].u[2 + m] = y;
        }
      }
      short8 vf0 = VREAD(cur, 0, ksc);
      short8 vf1 = VREAD(cur, 1, ksc);
      short8 vf2 = VREAD(cur, 2, ksc);
      short8 vf3 = VREAD(cur, 3, ksc);
      ao[0][0] = __builtin_amdgcn_mfma_f32_16x16x32_bf16(pa[0].s, vf0, ao[0][0], 0, 0, 0);
      ao[1][0] = __builtin_amdgcn_mfma_f32_16x16x32_bf16(pa[1].s, vf0, ao[1][0], 0, 0, 0);
      ao[0][1] = __builtin_amdgcn_mfma_f32_16x16x32_bf16(pa[0].s, vf1, ao[0][1], 0, 0, 0);
      ao[1][1] = __builtin_amdgcn_mfma_f32_16x16x32_bf16(pa[1].s, vf1, ao[1][1], 0, 0, 0);
      ao[0][2] = __builtin_amdgcn_mfma_f32_16x16x32_bf16(pa[0].s, vf2, ao[0][2], 0, 0, 0);
      ao[1][2] = __builtin_amdgcn_mfma_f32_16x16x32_bf16(pa[1].s, vf2, ao[1][2], 0, 0, 0);
      ao[0][3] = __builtin_amdgcn_mfma_f32_16x16x32_bf16(pa[0].s, vf3, ao[0][3], 0, 0, 0);
      ao[1][3] = __builtin_amdgcn_mfma_f32_16x16x32_bf16(pa[1].s, vf3, ao[1][3], 0, 0, 0);
    }

    // -- write tile t+1 into the other buffer (consumes in-flight loads;
    //    safe pre-barrier: no wave reads buf nxt during round t) --
    if (t < 3) {
      #pragma unroll
      for (int i = 0; i < 2; ++i) {
        float4 v = i ? kv1 : kv0;
        uint2 w;
        w.x = cvt_pk(v.x, v.y);
        w.y = cvt_pk(v.z, v.w);
        *reinterpret_cast<uint2*>(&Klds[nxt][(i * 32 + sQ) * KSTR + c4 * 4]) = w;
      }
      int spw = sQ ^ ((c4 & 7) << 2);
      #pragma unroll
      for (int k = 0; k < 4; ++k)
        Vt32[nxt][(c4 * 4 + k) * VSTRW + spw] = cvt_pk((&vv0.x)[k], (&vv1.x)[k]);
    }
    __syncthreads();
  }

  // ---- softmax denominators + epilogue (coalesced 64B row segments) ----
  #pragma unroll
  for (int p = 0; p < 2; ++p) {
    const int n0 = p * 128 + wave * 16;
    float s4 = (ps[p][0] + ps[p][1]) + (ps[p][2] + ps[p][3]);
    s4 += __shfl_xor(s4, 16);
    s4 += __shfl_xor(s4, 32);
    const float rcp = __builtin_amdgcn_rcpf(s4);
    float rcpv[4];
    #pragma unroll
    for (int r = 0; r < 4; ++r) rcpv[r] = __shfl(rcp, 4 * g + r);
    #pragma unroll
    for (int dt = 0; dt < 4; ++dt)
      #pragma unroll
      for (int r = 0; r < 4; ++r)
        O[base + (n0 + 4 * g + r) * 512 + dt * 16 + c] = ao[p][dt][r] * rcpv[r];
  }
#undef KREAD
#undef VREAD
}

extern "C" void kernel_launch(void* const* d_in, const int* in_sizes, int n_in,
                              void* d_out, int out_size, void* d_ws, size_t ws_size,
                              hipStream_t stream) {
  const float* Q = (const float*)d_in[0];
  const float* K = (const float*)d_in[1];
  const float* V = (const float*)d_in[2];
  float* O = (float*)d_out;
  attn_kernel<<<dim3(512), dim3(512), 0, stream>>>(Q, K, V, O);
}

// Round 18
// 35.470 us; speedup vs baseline: 1.5118x; 1.5007x over previous
//
#include <hip/hip_runtime.h>

// B=4, T=16, N=S=256, H=8, DK=DV=64, fp32 in/out.
// One block per (bt, h): 512 blocks x 512 threads (8 waves).
// Swapped QK^T (A=K, B=Q), no max-sub, scale*log2e folded into Q,
// permlane P exchange, V^T XOR bank-swizzle, plain coalesced stores.
// STREAMED K/V in four 64-row s-tiles, double-buffered LDS (36.9 KB).
// R13/R17 spilled: LDS 36.9KB allows 4 blocks/CU so the allocator squeezed
// VGPR to 64 (8 waves/SIMD bin) and spilled ~300B/thread (+113MB scratch).
// Fix: __launch_bounds__(512, 2) -> min 2 waves/EU -> 256-VGPR budget ->
// allocator uses ~110 regs, NO spill, runs at 4 waves/SIMD (same 16
// waves/CU as the 30.8us baseline but with staging overlapped).

typedef short short8 __attribute__((ext_vector_type(8)));
typedef float floatx4 __attribute__((ext_vector_type(4)));

__device__ __forceinline__ unsigned cvt_pk(float lo, float hi) {
  unsigned r;
  asm("v_cvt_pk_bf16_f32 %0, %1, %2" : "=v"(r) : "v"(lo), "v"(hi));
  return r;
}

constexpr int KSTR  = 72;   // K tile row stride in shorts (144 B)
constexpr int VSTRW = 36;   // V^T tile row stride in u32 words (144 B)

__global__ __launch_bounds__(512, 2) void attn_kernel(
    const float* __restrict__ Q, const float* __restrict__ K,
    const float* __restrict__ V, float* __restrict__ O) {
  __shared__ __align__(16) short    Klds[2][64 * KSTR];   // 2 x 9216 B
  __shared__ __align__(16) unsigned Vt32[2][64 * VSTRW];  // 2 x 9216 B (36864 total)

  const int inst = blockIdx.x;
  const int h    = inst & 7;
  const int bt   = inst >> 3;
  const int base = bt * (256 * 512) + h * 64;
  const int tid  = threadIdx.x;

  const int wave = tid >> 6;
  const int lane = tid & 63;
  const int c    = lane & 15;
  const int g    = lane >> 4;
  const int c4   = tid & 15;
  const int sQ   = tid >> 4;       // 0..31

  const float* Kb = K + base;
  const float* Vb = V + base;

  // ---- Q fragments for BOTH passes, scaled by 0.125*log2(e) ----
  const float SCQ = 0.125f * 1.4426950408889634f;
  short8 qf[2][2];
  #pragma unroll
  for (int p = 0; p < 2; ++p) {
    #pragma unroll
    for (int ks2 = 0; ks2 < 2; ++ks2) {
      const float* qp =
          Q + base + (p * 128 + wave * 16 + c) * 512 + ks2 * 32 + g * 8;
      float4 a = *reinterpret_cast<const float4*>(qp);
      float4 b = *reinterpret_cast<const float4*>(qp + 4);
      union { unsigned u[4]; short8 s; } t;
      t.u[0] = cvt_pk(a.x * SCQ, a.y * SCQ);
      t.u[1] = cvt_pk(a.z * SCQ, a.w * SCQ);
      t.u[2] = cvt_pk(b.x * SCQ, b.y * SCQ);
      t.u[3] = cvt_pk(b.z * SCQ, b.w * SCQ);
      qf[p][ks2] = t.s;
    }
  }

  // ---- prologue: stage tile 0 directly into buffer 0 ----
  #pragma unroll
  for (int i = 0; i < 2; ++i) {
    int sr = i * 32 + sQ;          // 0..63
    float4 v = *reinterpret_cast<const float4*>(Kb + sr * 512 + c4 * 4);
    uint2 w;
    w.x = cvt_pk(v.x, v.y);
    w.y = cvt_pk(v.z, v.w);
    *reinterpret_cast<uint2*>(&Klds[0][sr * KSTR + c4 * 4]) = w;
  }
  {
    int spw = sQ ^ ((c4 & 7) << 2);
    float4 v0 = *reinterpret_cast<const float4*>(Vb + (2 * sQ) * 512 + c4 * 4);
    float4 v1 = *reinterpret_cast<const float4*>(Vb + (2 * sQ + 1) * 512 + c4 * 4);
    #pragma unroll
    for (int k = 0; k < 4; ++k)
      Vt32[0][(c4 * 4 + k) * VSTRW + spw] = cvt_pk((&v0.x)[k], (&v1.x)[k]);
  }
  __syncthreads();

#define KREAD(buf, ts, half)                                       \
  (*reinterpret_cast<const short8*>(                               \
      &Klds[buf][((ts) * 16 + c) * KSTR + (half) * 32 + g * 8]))
#define VREAD(buf, dt, ksc)                                        \
  (*reinterpret_cast<const short8*>(reinterpret_cast<const short*>(\
      &Vt32[buf][((dt) * 16 + c) * VSTRW +                         \
                 (((ksc) * 16 + 4 * g) ^ (16 * ((dt) & 1) + (c & 12)))])))

  floatx4 ao[2][4];
  #pragma unroll
  for (int p = 0; p < 2; ++p)
    #pragma unroll
    for (int dt = 0; dt < 4; ++dt) ao[p][dt] = floatx4{0.f, 0.f, 0.f, 0.f};
  float ps[2][4] = {{0.f, 0.f, 0.f, 0.f}, {0.f, 0.f, 0.f, 0.f}};

  #pragma unroll
  for (int t = 0; t < 4; ++t) {
    const int cur = t & 1, nxt = cur ^ 1;

    // -- issue tile t+1 global loads into registers (land under compute) --
    float4 kv0, kv1, vv0, vv1;
    if (t < 3) {
      kv0 = *reinterpret_cast<const float4*>(
          Kb + ((t + 1) * 64 + sQ) * 512 + c4 * 4);
      kv1 = *reinterpret_cast<const float4*>(
          Kb + ((t + 1) * 64 + 32 + sQ) * 512 + c4 * 4);
      vv0 = *reinterpret_cast<const float4*>(
          Vb + ((t + 1) * 64 + 2 * sQ) * 512 + c4 * 4);
      vv1 = *reinterpret_cast<const float4*>(
          Vb + ((t + 1) * 64 + 2 * sQ + 1) * 512 + c4 * 4);
    }
    // pin the prefetch above the compute phase (no sinking to use-site)
    __builtin_amdgcn_sched_barrier(0);

    // -- QK^T + exp2 + pack for the 4 16-row subtiles of this tile --
    unsigned pk[2][4][2];   // [pass][subtile][m]
    #pragma unroll
    for (int ts = 0; ts < 4; ++ts) {
      short8 kf0 = KREAD(cur, ts, 0);
      short8 kf1 = KREAD(cur, ts, 1);
      #pragma unroll
      for (int p = 0; p < 2; ++p) {
        floatx4 z = {0.f, 0.f, 0.f, 0.f};
        floatx4 a0 = __builtin_amdgcn_mfma_f32_16x16x32_bf16(kf0, qf[p][0], z, 0, 0, 0);
        floatx4 a1 = __builtin_amdgcn_mfma_f32_16x16x32_bf16(kf1, qf[p][1], z, 0, 0, 0);
        float e0 = exp2f(a0[0] + a1[0]);
        float e1 = exp2f(a0[1] + a1[1]);
        float e2 = exp2f(a0[2] + a1[2]);
        float e3 = exp2f(a0[3] + a1[3]);
        ps[p][0] += e0; ps[p][1] += e1; ps[p][2] += e2; ps[p][3] += e3;
        pk[p][ts][0] = cvt_pk(e0, e1);
        pk[p][ts][1] = cvt_pk(e2, e3);
      }
    }

    // -- PV: 2 s-chunks of 32 per tile --
    #pragma unroll
    for (int ksc = 0; ksc < 2; ++ksc) {
      union { unsigned u[4]; short8 s; } pa[2];
      #pragma unroll
      for (int p = 0; p < 2; ++p) {
        #pragma unroll
        for (int m = 0; m < 2; ++m) {
          unsigned x = pk[p][2 * ksc][m], y = pk[p][2 * ksc + 1][m];
          asm("v_permlane32_swap_b32 %0, %1" : "+v"(x), "+v"(y));
          asm("v_permlane16_swap_b32 %0, %1" : "+v"(x), "+v"(y));
          pa[p].u[m]     = x;
          pa[p].u[2 + m] = y;
        }
      }
      short8 vf0 = VREAD(cur, 0, ksc);
      short8 vf1 = VREAD(cur, 1, ksc);
      short8 vf2 = VREAD(cur, 2, ksc);
      short8 vf3 = VREAD(cur, 3, ksc);
      ao[0][0] = __builtin_amdgcn_mfma_f32_16x16x32_bf16(pa[0].s, vf0, ao[0][0], 0, 0, 0);
      ao[1][0] = __builtin_amdgcn_mfma_f32_16x16x32_bf16(pa[1].s, vf0, ao[1][0], 0, 0, 0);
      ao[0][1] = __builtin_amdgcn_mfma_f32_16x16x32_bf16(pa[0].s, vf1, ao[0][1], 0, 0, 0);
      ao[1][1] = __builtin_amdgcn_mfma_f32_16x16x32_bf16(pa[1].s, vf1, ao[1][1], 0, 0, 0);
      ao[0][2] = __builtin_amdgcn_mfma_f32_16x16x32_bf16(pa[0].s, vf2, ao[0][2], 0, 0, 0);
      ao[1][2] = __builtin_amdgcn_mfma_f32_16x16x32_bf16(pa[1].s, vf2, ao[1][2], 0, 0, 0);
      ao[0][3] = __builtin_amdgcn_mfma_f32_16x16x32_bf16(pa[0].s, vf3, ao[0][3], 0, 0, 0);
      ao[1][3] = __builtin_amdgcn_mfma_f32_16x16x32_bf16(pa[1].s, vf3, ao[1][3], 0, 0, 0);
    }

    // -- write tile t+1 into the other buffer (consumes in-flight loads;
    //    safe pre-barrier: no wave reads buf nxt during round t) --
    if (t < 3) {
      #pragma unroll
      for (int i = 0; i < 2; ++i) {
        float4 v = i ? kv1 : kv0;
        uint2 w;
        w.x = cvt_pk(v.x, v.y);
        w.y = cvt_pk(v.z, v.w);
        *reinterpret_cast<uint2*>(&Klds[nxt][(i * 32 + sQ) * KSTR + c4 * 4]) = w;
      }
      int spw = sQ ^ ((c4 & 7) << 2);
      #pragma unroll
      for (int k = 0; k < 4; ++k)
        Vt32[nxt][(c4 * 4 + k) * VSTRW + spw] = cvt_pk((&vv0.x)[k], (&vv1.x)[k]);
    }
    __syncthreads();
  }

  // ---- softmax denominators + epilogue (coalesced 64B row segments) ----
  #pragma unroll
  for (int p = 0; p < 2; ++p) {
    const int n0 = p * 128 + wave * 16;
    float s4 = (ps[p][0] + ps[p][1]) + (ps[p][2] + ps[p][3]);
    s4 += __shfl_xor(s4, 16);
    s4 += __shfl_xor(s4, 32);
    const float rcp = __builtin_amdgcn_rcpf(s4);
    float rcpv[4];
    #pragma unroll
    for (int r = 0; r < 4; ++r) rcpv[r] = __shfl(rcp, 4 * g + r);
    #pragma unroll
    for (int dt = 0; dt < 4; ++dt)
      #pragma unroll
      for (int r = 0; r < 4; ++r)
        O[base + (n0 + 4 * g + r) * 512 + dt * 16 + c] = ao[p][dt][r] * rcpv[r];
  }
#undef KREAD
#undef VREAD
}

extern "C" void kernel_launch(void* const* d_in, const int* in_sizes, int n_in,
                              void* d_out, int out_size, void* d_ws, size_t ws_size,
                              hipStream_t stream) {
  const float* Q = (const float*)d_in[0];
  const float* K = (const float*)d_in[1];
  const float* V = (const float*)d_in[2];
  float* O = (float*)d_out;
  attn_kernel<<<dim3(512), dim3(512), 0, stream>>>(Q, K, V, O);
}

// Round 19
// 33.799 us; speedup vs baseline: 1.5865x; 1.0494x over previous
//
#include <hip/hip_runtime.h>

// B=4, T=16, N=S=256, H=8, DK=DV=64, fp32 in/out.
// One block per (bt, h): 512 blocks x 512 threads (8 waves).
// R8 skeleton (stage K+V once, one barrier, merged loop) with the math
// retiled to 32x32x16 MFMAs: single pass (wave owns 32 n-cols), half the
// LDS b128 reads per MAC, 4 permlane32_swap per chunk for the P exchange.
// Swapped QK^T (A=K, B=Q), no max-sub, scale*log2e folded into Q,
// V^T XOR bank-swizzle, coalesced dword stores.

typedef short short8 __attribute__((ext_vector_type(8)));
typedef float floatx16 __attribute__((ext_vector_type(16)));

__device__ __forceinline__ unsigned cvt_pk(float lo, float hi) {
  unsigned r;
  asm("v_cvt_pk_bf16_f32 %0, %1, %2" : "=v"(r) : "v"(lo), "v"(hi));
  return r;
}

constexpr int KSTR  = 72;    // K row stride in shorts (144 B)
constexpr int VSTRW = 132;   // V^T row stride in u32 words (528 B)

__global__ __launch_bounds__(512, 2) void attn_kernel(
    const float* __restrict__ Q, const float* __restrict__ K,
    const float* __restrict__ V, float* __restrict__ O) {
  __shared__ __align__(16) short    Klds[256 * KSTR];   // 36864 B
  __shared__ __align__(16) unsigned Vt32[64 * VSTRW];   // 33792 B (70656 total)

  const int inst = blockIdx.x;
  const int h8   = inst & 7;
  const int bt   = inst >> 3;
  const int base = bt * (256 * 512) + h8 * 64;
  const int tid  = threadIdx.x;

  const int wave = tid >> 6;
  const int lane = tid & 63;
  const int r31  = lane & 31;    // A-row / B-col index
  const int h    = lane >> 5;    // k-group half
  const int c4   = tid & 15;
  const int sQ   = tid >> 4;     // 0..31 (within-wave staging index uses tid)

  // ---- stage K: 256x64 fp32 -> bf16 LDS ----
  {
    const float* Kb = K + base;
    #pragma unroll
    for (int i = 0; i < 8; ++i) {
      int idx = i * 512 + tid;
      int s = idx >> 4, cc = idx & 15;
      float4 v = *reinterpret_cast<const float4*>(Kb + s * 512 + cc * 4);
      uint2 w;
      w.x = cvt_pk(v.x, v.y);
      w.y = cvt_pk(v.z, v.w);
      *reinterpret_cast<uint2*>(&Klds[s * KSTR + cc * 4]) = w;
    }
  }
  // ---- stage V^T with XOR bank swizzle (word col sp stored at sp^((d>>2&7)<<2)) ----
  {
    const float* Vb = V + base;
    #pragma unroll
    for (int i = 0; i < 4; ++i) {
      int idx = i * 512 + tid;
      int sp = idx >> 4, cc = idx & 15;
      int s = sp * 2;
      int spw = sp ^ ((cc & 7) << 2);
      float4 v0 = *reinterpret_cast<const float4*>(Vb + s * 512 + cc * 4);
      float4 v1 = *reinterpret_cast<const float4*>(Vb + (s + 1) * 512 + cc * 4);
      #pragma unroll
      for (int k = 0; k < 4; ++k)
        Vt32[(cc * 4 + k) * VSTRW + spw] = cvt_pk((&v0.x)[k], (&v1.x)[k]);
    }
  }

  // ---- Q B-fragments: col n = wave*32 + r31, k(d) = 16*kc + 8*h + j ----
  const float SCQ = 0.125f * 1.4426950408889634f;
  const int nq = wave * 32 + r31;
  short8 qf[4];
  #pragma unroll
  for (int kc = 0; kc < 4; ++kc) {
    const float* qp = Q + base + nq * 512 + 16 * kc + 8 * h;
    float4 a = *reinterpret_cast<const float4*>(qp);
    float4 b = *reinterpret_cast<const float4*>(qp + 4);
    union { unsigned u[4]; short8 s; } t;
    t.u[0] = cvt_pk(a.x * SCQ, a.y * SCQ);
    t.u[1] = cvt_pk(a.z * SCQ, a.w * SCQ);
    t.u[2] = cvt_pk(b.x * SCQ, b.y * SCQ);
    t.u[3] = cvt_pk(b.z * SCQ, b.w * SCQ);
    qf[kc] = t.s;
  }
  __syncthreads();

  const int swzr = ((r31 >> 2) & 7) << 2;   // V read-side XOR (bits 2..4)

  floatx16 ao0 = {}, ao1 = {};
  float ps[4] = {0.f, 0.f, 0.f, 0.f};

  #pragma unroll
  for (int it = 0; it < 8; ++it) {
    // -- QK^T: C[s=32it+sl][n], 4 chained 32x32x16 MFMAs over d --
    floatx16 sc = {};
    #pragma unroll
    for (int kc = 0; kc < 4; ++kc) {
      short8 kf = *reinterpret_cast<const short8*>(
          &Klds[(32 * it + r31) * KSTR + 16 * kc + 8 * h]);
      sc = __builtin_amdgcn_mfma_f32_32x32x16_bf16(kf, qf[kc], sc, 0, 0, 0);
    }

    // -- exp2 + partial sums + pack (reg -> s_local = (reg&3)+8*(reg>>2)+4h) --
    unsigned pk[8];
    #pragma unroll
    for (int q = 0; q < 4; ++q) {
      float e0 = exp2f(sc[4 * q + 0]);
      float e1 = exp2f(sc[4 * q + 1]);
      float e2 = exp2f(sc[4 * q + 2]);
      float e3 = exp2f(sc[4 * q + 3]);
      ps[q] += (e0 + e1) + (e2 + e3);
      pk[2 * q]     = cvt_pk(e0, e1);
      pk[2 * q + 1] = cvt_pk(e2, e3);
    }

    // -- P exchange: 4 permlane32_swap build both PV A-frags --
    union { unsigned u[4]; short8 s; } pa0, pa1;
    {
      unsigned x, y;
      x = pk[0]; y = pk[2];
      asm("v_permlane32_swap_b32 %0, %1" : "+v"(x), "+v"(y));
      pa0.u[0] = x; pa0.u[2] = y;
      x = pk[1]; y = pk[3];
      asm("v_permlane32_swap_b32 %0, %1" : "+v"(x), "+v"(y));
      pa0.u[1] = x; pa0.u[3] = y;
      x = pk[4]; y = pk[6];
      asm("v_permlane32_swap_b32 %0, %1" : "+v"(x), "+v"(y));
      pa1.u[0] = x; pa1.u[2] = y;
      x = pk[5]; y = pk[7];
      asm("v_permlane32_swap_b32 %0, %1" : "+v"(x), "+v"(y));
      pa1.u[1] = x; pa1.u[3] = y;
    }

    // -- PV: D[n][d] col=d; B = V[s][d] from Vt rows (d = db*32 + r31) --
    {
      const unsigned* vrow0 = &Vt32[(r31) * VSTRW];
      const unsigned* vrow1 = &Vt32[(32 + r31) * VSTRW];
      short8 vf00 = *reinterpret_cast<const short8*>(
          vrow0 + ((16 * it + 4 * h) ^ swzr));
      short8 vf01 = *reinterpret_cast<const short8*>(
          vrow0 + ((16 * it + 8 + 4 * h) ^ swzr));
      short8 vf10 = *reinterpret_cast<const short8*>(
          vrow1 + ((16 * it + 4 * h) ^ swzr));
      short8 vf11 = *reinterpret_cast<const short8*>(
          vrow1 + ((16 * it + 8 + 4 * h) ^ swzr));
      ao0 = __builtin_amdgcn_mfma_f32_32x32x16_bf16(pa0.s, vf00, ao0, 0, 0, 0);
      ao0 = __builtin_amdgcn_mfma_f32_32x32x16_bf16(pa1.s, vf01, ao0, 0, 0, 0);
      ao1 = __builtin_amdgcn_mfma_f32_32x32x16_bf16(pa0.s, vf10, ao1, 0, 0, 0);
      ao1 = __builtin_amdgcn_mfma_f32_32x32x16_bf16(pa1.s, vf11, ao1, 0, 0, 0);
    }
  }

  // ---- denominator + epilogue ----
  float pstot = (ps[0] + ps[1]) + (ps[2] + ps[3]);
  pstot += __shfl_xor(pstot, 32);
  const float rcp = __builtin_amdgcn_rcpf(pstot);   // for n-col = r31 (this wave)

  float rcpv[16];
  #pragma unroll
  for (int reg = 0; reg < 16; ++reg)
    rcpv[reg] = __shfl(rcp, (reg & 3) + 8 * (reg >> 2) + 4 * h);

  #pragma unroll
  for (int reg = 0; reg < 16; ++reg) {
    int n = wave * 32 + (reg & 3) + 8 * (reg >> 2) + 4 * h;
    O[base + n * 512 + r31]      = ao0[reg] * rcpv[reg];
    O[base + n * 512 + 32 + r31] = ao1[reg] * rcpv[reg];
  }
}

extern "C" void kernel_launch(void* const* d_in, const int* in_sizes, int n_in,
                              void* d_out, int out_size, void* d_ws, size_t ws_size,
                              hipStream_t stream) {
  const float* Q = (const float*)d_in[0];
  const float* K = (const float*)d_in[1];
  const float* V = (const float*)d_in[2];
  float* O = (float*)d_out;
  attn_kernel<<<dim3(512), dim3(512), 0, stream>>>(Q, K, V, O);
}

// Round 20
// 32.330 us; speedup vs baseline: 1.6586x; 1.0454x over previous
//
#include <hip/hip_runtime.h>

// B=4, T=16, N=S=256, H=8, DK=DV=64, fp32 in/out.
// 256 blocks x 1024 threads (16 waves); each block owns TWO (bt,h)
// instances with full double-buffered LDS (141 KB): stage0 -> barrier ->
// [stage1 || compute0] (no barrier inside: different LDS buffers) ->
// barrier -> [O0 stores || compute1] -> O1. Cross-instance pipelining
// keeps the memory system busy during compute without fighting the
// vmcnt-drain-at-barrier semantics. Per-wave: single n-pass of 16 cols.
// Math identical to the verified R5 kernel (swapped QK^T, no max-sub,
// scale*log2e in Q, permlane P exchange, V^T XOR bank-swizzle).

typedef short short8 __attribute__((ext_vector_type(8)));
typedef float floatx4 __attribute__((ext_vector_type(4)));

__device__ __forceinline__ unsigned cvt_pk(float lo, float hi) {
  unsigned r;
  asm("v_cvt_pk_bf16_f32 %0, %1, %2" : "=v"(r) : "v"(lo), "v"(hi));
  return r;
}

constexpr int KSTR  = 72;    // K row stride in shorts (144 B)
constexpr int VSTRW = 132;   // V^T row stride in u32 words (528 B)

__device__ __forceinline__ void stage_kv(const float* __restrict__ Kb,
                                         const float* __restrict__ Vb,
                                         short* Kl, unsigned* Vt, int tid) {
  #pragma unroll
  for (int i = 0; i < 4; ++i) {
    int idx = i * 1024 + tid;
    int s = idx >> 4, cc = idx & 15;
    float4 v = *reinterpret_cast<const float4*>(Kb + s * 512 + cc * 4);
    uint2 w;
    w.x = cvt_pk(v.x, v.y);
    w.y = cvt_pk(v.z, v.w);
    *reinterpret_cast<uint2*>(&Kl[s * KSTR + cc * 4]) = w;
  }
  #pragma unroll
  for (int i = 0; i < 2; ++i) {
    int idx = i * 1024 + tid;
    int sp = idx >> 4, cc = idx & 15;
    int s = sp * 2;
    int spw = sp ^ ((cc & 7) << 2);
    float4 v0 = *reinterpret_cast<const float4*>(Vb + s * 512 + cc * 4);
    float4 v1 = *reinterpret_cast<const float4*>(Vb + (s + 1) * 512 + cc * 4);
    #pragma unroll
    for (int k = 0; k < 4; ++k)
      Vt[(cc * 4 + k) * VSTRW + spw] = cvt_pk((&v0.x)[k], (&v1.x)[k]);
  }
}

__global__ __launch_bounds__(1024, 4) void attn_kernel(
    const float* __restrict__ Q, const float* __restrict__ K,
    const float* __restrict__ V, float* __restrict__ O) {
  __shared__ __align__(16) short    Klds[2][256 * KSTR];   // 2 x 36864 B
  __shared__ __align__(16) unsigned Vt32[2][64 * VSTRW];   // 2 x 33792 B (141312)

  const int tid  = threadIdx.x;
  const int wave = tid >> 6;          // 0..15 -> n-block
  const int lane = tid & 63;
  const int c    = lane & 15;
  const int g    = lane >> 4;

  const int i0    = blockIdx.x * 2;
  const int i1    = i0 + 1;
  const int base0 = (i0 >> 3) * (256 * 512) + (i0 & 7) * 64;
  const int base1 = (i1 >> 3) * (256 * 512) + (i1 & 7) * 64;

  const float SCQ = 0.125f * 1.4426950408889634f;

#define LOADQ(qf, gbase)                                                     \
  {                                                                          \
    _Pragma("unroll")                                                        \
    for (int ks2 = 0; ks2 < 2; ++ks2) {                                      \
      const float* qp = Q + (gbase) + (wave * 16 + c) * 512 + ks2 * 32 + g * 8; \
      float4 a  = *reinterpret_cast<const float4*>(qp);                      \
      float4 bb = *reinterpret_cast<const float4*>(qp + 4);                  \
      union { unsigned u[4]; short8 s; } t;                                  \
      t.u[0] = cvt_pk(a.x * SCQ, a.y * SCQ);                                 \
      t.u[1] = cvt_pk(a.z * SCQ, a.w * SCQ);                                 \
      t.u[2] = cvt_pk(bb.x * SCQ, bb.y * SCQ);                               \
      t.u[3] = cvt_pk(bb.z * SCQ, bb.w * SCQ);                               \
      qf[ks2] = t.s;                                                         \
    }                                                                        \
  }

#define COMPUTE(b, qf, ao, ps)                                               \
  _Pragma("unroll")                                                          \
  for (int ks = 0; ks < 8; ++ks) {                                           \
    unsigned pk2[2][2];                                                      \
    _Pragma("unroll")                                                        \
    for (int tt = 0; tt < 2; ++tt) {                                         \
      const int t = 2 * ks + tt;                                             \
      short8 kf0 = *reinterpret_cast<const short8*>(                         \
          &Klds[b][(t * 16 + c) * KSTR + g * 8]);                            \
      short8 kf1 = *reinterpret_cast<const short8*>(                         \
          &Klds[b][(t * 16 + c) * KSTR + 32 + g * 8]);                       \
      floatx4 acc = {0.f, 0.f, 0.f, 0.f};                                    \
      acc = __builtin_amdgcn_mfma_f32_16x16x32_bf16(kf0, qf[0], acc, 0, 0, 0); \
      acc = __builtin_amdgcn_mfma_f32_16x16x32_bf16(kf1, qf[1], acc, 0, 0, 0); \
      float e0 = exp2f(acc[0]);                                              \
      float e1 = exp2f(acc[1]);                                              \
      float e2 = exp2f(acc[2]);                                              \
      float e3 = exp2f(acc[3]);                                              \
      ps[0] += e0; ps[1] += e1; ps[2] += e2; ps[3] += e3;                    \
      pk2[tt][0] = cvt_pk(e0, e1);                                           \
      pk2[tt][1] = cvt_pk(e2, e3);                                           \
    }                                                                        \
    union { unsigned u[4]; short8 s; } pa;                                   \
    _Pragma("unroll")                                                        \
    for (int m = 0; m < 2; ++m) {                                            \
      unsigned x = pk2[0][m], y = pk2[1][m];                                 \
      asm("v_permlane32_swap_b32 %0, %1" : "+v"(x), "+v"(y));                \
      asm("v_permlane16_swap_b32 %0, %1" : "+v"(x), "+v"(y));                \
      pa.u[m]     = x;                                                       \
      pa.u[2 + m] = y;                                                       \
    }                                                                        \
    _Pragma("unroll")                                                        \
    for (int dt = 0; dt < 4; ++dt) {                                         \
      short8 vf = *reinterpret_cast<const short8*>(                          \
          reinterpret_cast<const short*>(                                    \
              &Vt32[b][(dt * 16 + c) * VSTRW +                               \
                       ((ks * 16 + 4 * g) ^ (16 * (dt & 1) + (c & 12)))]));  \
      ao[dt] = __builtin_amdgcn_mfma_f32_16x16x32_bf16(pa.s, vf, ao[dt], 0, 0, 0); \
    }                                                                        \
  }

#define EPILOGUE(ao, ps, gbase)                                              \
  {                                                                          \
    float s4 = (ps[0] + ps[1]) + (ps[2] + ps[3]);                            \
    s4 += __shfl_xor(s4, 16);                                                \
    s4 += __shfl_xor(s4, 32);                                                \
    const float rcp = __builtin_amdgcn_rcpf(s4);                             \
    float rcpv[4];                                                           \
    _Pragma("unroll")                                                        \
    for (int r = 0; r < 4; ++r) rcpv[r] = __shfl(rcp, 4 * g + r);            \
    _Pragma("unroll")                                                        \
    for (int dt = 0; dt < 4; ++dt)                                           \
      _Pragma("unroll")                                                      \
      for (int r = 0; r < 4; ++r)                                            \
        O[(gbase) + (wave * 16 + 4 * g + r) * 512 + dt * 16 + c] =           \
            ao[dt][r] * rcpv[r];                                             \
  }

  // ---- phase 0: stage instance 0, load its Q fragments ----
  short8 qf0[2], qf1[2];
  LOADQ(qf0, base0);
  stage_kv(K + base0, V + base0, Klds[0], Vt32[0], tid);
  __syncthreads();   // buf0 ready

  // ---- phase A: stage instance 1 (source-first: loads issue early),
  //      then compute instance 0 — compiler interleaves freely (no barrier,
  //      disjoint LDS buffers) ----
  LOADQ(qf1, base1);
  stage_kv(K + base1, V + base1, Klds[1], Vt32[1], tid);

  floatx4 ao0[4] = {{0.f,0.f,0.f,0.f},{0.f,0.f,0.f,0.f},
                    {0.f,0.f,0.f,0.f},{0.f,0.f,0.f,0.f}};
  float ps0[4] = {0.f, 0.f, 0.f, 0.f};
  COMPUTE(0, qf0, ao0, ps0);
  __syncthreads();   // buf1 ready; all waves done reading buf0

  // ---- phase B: O0 stores overlap compute of instance 1 ----
  EPILOGUE(ao0, ps0, base0);

  floatx4 ao1[4] = {{0.f,0.f,0.f,0.f},{0.f,0.f,0.f,0.f},
                    {0.f,0.f,0.f,0.f},{0.f,0.f,0.f,0.f}};
  float ps1[4] = {0.f, 0.f, 0.f, 0.f};
  COMPUTE(1, qf1, ao1, ps1);
  EPILOGUE(ao1, ps1, base1);

#undef LOADQ
#undef COMPUTE
#undef EPILOGUE
}

extern "C" void kernel_launch(void* const* d_in, const int* in_sizes, int n_in,
                              void* d_out, int out_size, void* d_ws, size_t ws_size,
                              hipStream_t stream) {
  const float* Q = (const float*)d_in[0];
  const float* K = (const float*)d_in[1];
  const float* V = (const float*)d_in[2];
  float* O = (float*)d_out;
  attn_kernel<<<dim3(256), dim3(1024), 0, stream>>>(Q, K, V, O);
}